// Round 1
// baseline (1001.468 us; speedup 1.0000x reference)
//
#include <hip/hip_runtime.h>
#include <math.h>

#define TOPK 16

__device__ __forceinline__ float waveMax(float v) {
  #pragma unroll
  for (int o = 32; o > 0; o >>= 1) v = fmaxf(v, __shfl_down(v, o, 64));
  return v;
}
__device__ __forceinline__ float waveSum(float v) {
  #pragma unroll
  for (int o = 32; o > 0; o >>= 1) v += __shfl_down(v, o, 64);
  return v;
}

// One block per row. 3 streaming passes over the row (re-reads hit L2/LLC),
// then a 16-thread sparse fixup for the scattered kernel-weight positions.
__global__ __launch_bounds__(256) void combiner_kernel(
    const float* __restrict__ logits,
    const float* __restrict__ dist,
    const int*   __restrict__ tok,
    float* __restrict__ out,
    int V)
{
  const int row = blockIdx.x;
  const int tid = threadIdx.x;
  const int nthreads = blockDim.x;           // 256
  const size_t base = (size_t)row * (size_t)V;
  const float4* lrow = reinterpret_cast<const float4*>(logits + base);
  float4* orow = reinterpret_cast<float4*>(out + base);
  const int nvec = V >> 2;                   // V divisible by 4 (32000)

  __shared__ float red[4];
  __shared__ float s_m, s_Z, s_logZ;

  const int wave = tid >> 6;
  const int lane = tid & 63;
  const int nwaves = nthreads >> 6;

  // ---- pass 1: row max ----
  float m = -INFINITY;
  for (int i = tid; i < nvec; i += nthreads) {
    float4 x = lrow[i];
    m = fmaxf(m, fmaxf(fmaxf(x.x, x.y), fmaxf(x.z, x.w)));
  }
  m = waveMax(m);
  if (lane == 0) red[wave] = m;
  __syncthreads();
  if (tid == 0) {
    float mm = red[0];
    for (int w = 1; w < nwaves; ++w) mm = fmaxf(mm, red[w]);
    s_m = mm;
  }
  __syncthreads();
  m = s_m;

  // ---- pass 2: Z = sum exp(x - m) ----
  float s = 0.f;
  for (int i = tid; i < nvec; i += nthreads) {
    float4 x = lrow[i];
    s += __expf(x.x - m) + __expf(x.y - m) + __expf(x.z - m) + __expf(x.w - m);
  }
  s = waveSum(s);
  __syncthreads();   // protect red[] reuse
  if (lane == 0) red[wave] = s;
  __syncthreads();
  if (tid == 0) {
    float ss = 0.f;
    for (int w = 0; w < nwaves; ++w) ss += red[w];
    s_Z = ss;
    s_logZ = logf(ss);
  }
  __syncthreads();
  const float Z = s_Z;
  // For non-scattered v: log(0.7 * exp(x-m)/Z) = x + (log0.7 - m - logZ)
  const float c = logf(0.7f) - m - s_logZ;

  // ---- pass 3: linear output for all positions ----
  for (int i = tid; i < nvec; i += nthreads) {
    float4 x = lrow[i];
    float4 o;
    o.x = x.x + c; o.y = x.y + c; o.z = x.z + c; o.w = x.w + c;
    orow[i] = o;
  }
  __syncthreads();   // s_waitcnt vmcnt(0)+s_barrier: orders pass-3 stores before fixup stores

  // ---- fixup: the <=16 scattered positions per row ----
  if (tid < TOPK) {
    const float* drow = dist + (size_t)row * TOPK;
    const int*   trow = tok  + (size_t)row * TOPK;
    // softmax over -d/100 across the 16 neighbors (redundant per thread; trivial)
    float nd[TOPK];
    #pragma unroll
    for (int j = 0; j < TOPK; ++j) nd[j] = -drow[j] * 0.01f;
    float dmax = -INFINITY;
    #pragma unroll
    for (int j = 0; j < TOPK; ++j) dmax = fmaxf(dmax, nd[j]);
    float dsum = 0.f;
    #pragma unroll
    for (int j = 0; j < TOPK; ++j) dsum += __expf(nd[j] - dmax);
    const int t = trow[tid];
    // duplicate-safe: accumulate ALL weights landing on token t; duplicate
    // threads compute the identical value, so the write race is benign.
    float e = 0.f;
    #pragma unroll
    for (int j = 0; j < TOPK; ++j)
      if (trow[j] == t) e += __expf(nd[j] - dmax);
    e /= dsum;
    const float x = logits[base + (size_t)t];
    const float p = __expf(x - m) / Z;
    out[base + (size_t)t] = logf(0.7f * p + 0.3f * e);
  }
}

extern "C" void kernel_launch(void* const* d_in, const int* in_sizes, int n_in,
                              void* d_out, int out_size, void* d_ws, size_t ws_size,
                              hipStream_t stream) {
  // inputs: 0=hidden (unused), 1=logits fp32 (N*V), 2=distances fp32 (N*16),
  //         3=token_indices int32 (N*16)
  const float* logits = (const float*)d_in[1];
  const float* dist   = (const float*)d_in[2];
  const int*   tok    = (const int*)d_in[3];
  float* out = (float*)d_out;

  const int N = in_sizes[2] / TOPK;      // 4096
  const int V = in_sizes[1] / N;         // 32000

  combiner_kernel<<<dim3(N), dim3(256), 0, stream>>>(logits, dist, tok, out, V);
}